// Round 9
// baseline (36.779 us; speedup 1.0000x reference)
//
#include <hip/hip_runtime.h>
#include <hip/hip_fp16.h>
#include <math.h>

#define IN_DIM 256
#define L1_DIM 16
#define N_ETYPE_MAX 1000

typedef _Float16 f16x8 __attribute__((ext_vector_type(8)));
typedef float f32x4 __attribute__((ext_vector_type(4)));

// ---------------- proj kernel (MFMA f16) ----------------
// GEMM M=n_nodes, N=32 ([w1|w2]), K=256 via mfma_f32_16x16x32_f16.
// Block = 256 = 4 waves, M=64 nodes/block, wave w owns rows 16w..16w+15.
// No LDS, no barrier. Trailing 8 blocks build the INTERLEAVED fp16 level-2
// table wq[t] = [w1_l2[t][0..15] | w2_l2[t][0..15]] (64 B per type).
__global__ __launch_bounds__(256) void proj_kernel(
    const float* __restrict__ z,
    const float* __restrict__ w1,     // [256][16]
    const float* __restrict__ w2,
    const float* __restrict__ w1_l2,  // [1000][16]
    const float* __restrict__ w2_l2,
    __half* __restrict__ h1,          // [n_nodes][16] fp16
    __half* __restrict__ h2,
    __half* __restrict__ wq,          // [n_types][32] interleaved fp16
    int n_nodes, int n_l2, int nblocks_proj) {
  // trailing blocks: build interleaved fp16 level-2 table
  if ((int)blockIdx.x >= nblocks_proj) {
    int t0 = ((int)blockIdx.x - nblocks_proj) * 256 + (int)threadIdx.x;
    for (int i = t0; i < n_l2; i += 8 * 256) {
      int t = i >> 4;
      int j = i & 15;
      wq[t * 32 + j]      = __float2half(w1_l2[i]);
      wq[t * 32 + 16 + j] = __float2half(w2_l2[i]);
    }
    return;
  }

  const int tid  = (int)threadIdx.x;
  const int lane = tid & 63;
  const int wv   = tid >> 6;      // 0..3
  const int r    = lane & 15;     // A row-in-tile / B col / D col
  const int q    = lane >> 4;     // k-subgroup 0..3
  const int node0 = (int)blockIdx.x * 64;

  // ---- B fragments: k = 32s + 8q + j, col = r ----
  f16x8 bf1[8], bf2[8];
#pragma unroll
  for (int s = 0; s < 8; ++s) {
#pragma unroll
    for (int j = 0; j < 8; ++j) {
      int k = 32 * s + 8 * q + j;
      bf1[s][j] = (_Float16)w1[k * L1_DIM + r];
      bf2[s][j] = (_Float16)w2[k * L1_DIM + r];
    }
  }

  // ---- A row pointer (clamped for tail block) ----
  int arow = node0 + wv * 16 + r;
  int ar = arow < n_nodes ? arow : (n_nodes - 1);
  const float* zrow = z + (size_t)ar * IN_DIM + 8 * q;

  f32x4 acc1 = {0.f, 0.f, 0.f, 0.f};
  f32x4 acc2 = {0.f, 0.f, 0.f, 0.f};

#pragma unroll
  for (int s = 0; s < 8; ++s) {
    float4 lo = *reinterpret_cast<const float4*>(zrow + 32 * s);
    float4 hi = *reinterpret_cast<const float4*>(zrow + 32 * s + 4);
    f16x8 af;
    af[0] = (_Float16)lo.x; af[1] = (_Float16)lo.y;
    af[2] = (_Float16)lo.z; af[3] = (_Float16)lo.w;
    af[4] = (_Float16)hi.x; af[5] = (_Float16)hi.y;
    af[6] = (_Float16)hi.z; af[7] = (_Float16)hi.w;
    acc1 = __builtin_amdgcn_mfma_f32_16x16x32_f16(af, bf1[s], acc1, 0, 0, 0);
    acc2 = __builtin_amdgcn_mfma_f32_16x16x32_f16(af, bf2[s], acc2, 0, 0, 0);
  }

  // ---- D layout: col = r, row = 4q + i -> node = node0 + 16wv + 4q + i ----
#pragma unroll
  for (int i = 0; i < 4; ++i) {
    int node = node0 + wv * 16 + 4 * q + i;
    if (node < n_nodes) {
      h1[(size_t)node * L1_DIM + r] = __float2half(fmaxf(acc1[i], 0.f));
      h2[(size_t)node * L1_DIM + r] = __float2half(fmaxf(acc2[i], 0.f));
    }
  }
}

// ---------------- edge kernel ----------------
// 2 lanes per edge, 4 EDGES PER PAIR PER ITERATION:
//  - indices via three int4 loads (16B coalesced per stream)
//  - 8 independent h-gathers + 8 ds_reads issued back-to-back (deep MLP)
//  - w table staged in LDS (off the VMEM port)
//  - lane0 of each pair stores a float4 of sigmoids (coalesced out)
union F4H { float4 f; __half2 h[4]; };

__device__ __forceinline__ float dot16(const F4H& a, const F4H& u,
                                       const F4H& b, const F4H& v) {
  float s = 0.f;
#pragma unroll
  for (int p = 0; p < 4; ++p) {
    s = __builtin_amdgcn_fdot2(a.h[p], u.h[p], s, false);
    s = __builtin_amdgcn_fdot2(b.h[p], v.h[p], s, false);
  }
  return s;
}

__global__ __launch_bounds__(512) void edge_kernel(
    const int* __restrict__ edge_index,  // [2][n_edges] (int32)
    const int* __restrict__ edge_type,   // [n_edges]
    const __half* __restrict__ h1,
    const __half* __restrict__ h2,
    const __half* __restrict__ wq,       // [1000][32] interleaved fp16
    float* __restrict__ out,
    int n_edges, int n_types) {
  __shared__ __align__(16) __half wl[N_ETYPE_MAX * 32];  // 62.5 KB

  const int tid = (int)threadIdx.x;

  // stage interleaved w table: coalesced float4 copies
  {
    const float4* srcp = reinterpret_cast<const float4*>(wq);
    float4* dstp = reinterpret_cast<float4*>(wl);
    int nf4 = n_types * 4;  // 32 halves = 4 float4 per type
    for (int i = tid; i < nf4; i += 512) dstp[i] = srcp[i];
  }
  __syncthreads();

  const int q = tid & 1;
  const int pair = tid >> 1;                    // 0..255
  const int gpair = (int)blockIdx.x * 256 + pair;
  const int npairs = (int)gridDim.x * 256;
  const bool aligned4 = (n_edges & 3) == 0;

  for (int e0 = gpair * 4; e0 < n_edges; e0 += npairs * 4) {
    if (aligned4 && e0 + 4 <= n_edges) {
      int4 sv = *reinterpret_cast<const int4*>(edge_index + e0);
      int4 dv = *reinterpret_cast<const int4*>(edge_index + n_edges + e0);
      int4 tv = *reinterpret_cast<const int4*>(edge_type + e0);

      F4H a0, a1, a2, a3, b0, b1, b2, b3;
      a0.f = *reinterpret_cast<const float4*>(h1 + (size_t)sv.x * L1_DIM + q * 8);
      a1.f = *reinterpret_cast<const float4*>(h1 + (size_t)sv.y * L1_DIM + q * 8);
      a2.f = *reinterpret_cast<const float4*>(h1 + (size_t)sv.z * L1_DIM + q * 8);
      a3.f = *reinterpret_cast<const float4*>(h1 + (size_t)sv.w * L1_DIM + q * 8);
      b0.f = *reinterpret_cast<const float4*>(h2 + (size_t)dv.x * L1_DIM + q * 8);
      b1.f = *reinterpret_cast<const float4*>(h2 + (size_t)dv.y * L1_DIM + q * 8);
      b2.f = *reinterpret_cast<const float4*>(h2 + (size_t)dv.z * L1_DIM + q * 8);
      b3.f = *reinterpret_cast<const float4*>(h2 + (size_t)dv.w * L1_DIM + q * 8);

      F4H u0, u1, u2, u3, v0, v1, v2, v3;
      u0.f = *reinterpret_cast<const float4*>(wl + tv.x * 32 + q * 8);
      v0.f = *reinterpret_cast<const float4*>(wl + tv.x * 32 + 16 + q * 8);
      u1.f = *reinterpret_cast<const float4*>(wl + tv.y * 32 + q * 8);
      v1.f = *reinterpret_cast<const float4*>(wl + tv.y * 32 + 16 + q * 8);
      u2.f = *reinterpret_cast<const float4*>(wl + tv.z * 32 + q * 8);
      v2.f = *reinterpret_cast<const float4*>(wl + tv.z * 32 + 16 + q * 8);
      u3.f = *reinterpret_cast<const float4*>(wl + tv.w * 32 + q * 8);
      v3.f = *reinterpret_cast<const float4*>(wl + tv.w * 32 + 16 + q * 8);

      float s0 = dot16(a0, u0, b0, v0);
      float s1 = dot16(a1, u1, b1, v1);
      float s2 = dot16(a2, u2, b2, v2);
      float s3 = dot16(a3, u3, b3, v3);

      s0 += __shfl_xor(s0, 1);
      s1 += __shfl_xor(s1, 1);
      s2 += __shfl_xor(s2, 1);
      s3 += __shfl_xor(s3, 1);

      if (q == 0) {
        float4 o;
        o.x = 1.0f / (1.0f + __expf(-s0));
        o.y = 1.0f / (1.0f + __expf(-s1));
        o.z = 1.0f / (1.0f + __expf(-s2));
        o.w = 1.0f / (1.0f + __expf(-s3));
        *reinterpret_cast<float4*>(out + e0) = o;
      }
    } else {
      // tail / unaligned fallback: per-edge scalar path
      for (int e = e0; e < e0 + 4 && e < n_edges; ++e) {
        int srci = edge_index[e];
        int dsti = edge_index[n_edges + e];
        int t    = edge_type[e];
        F4H a, b, u, v;
        a.f = *reinterpret_cast<const float4*>(h1 + (size_t)srci * L1_DIM + q * 8);
        b.f = *reinterpret_cast<const float4*>(h2 + (size_t)dsti * L1_DIM + q * 8);
        u.f = *reinterpret_cast<const float4*>(wl + t * 32 + q * 8);
        v.f = *reinterpret_cast<const float4*>(wl + t * 32 + 16 + q * 8);
        float s = dot16(a, u, b, v);
        s += __shfl_xor(s, 1);
        if (q == 0) out[e] = 1.0f / (1.0f + __expf(-s));
      }
    }
  }
}

extern "C" void kernel_launch(void* const* d_in, const int* in_sizes, int n_in,
                              void* d_out, int out_size, void* d_ws, size_t ws_size,
                              hipStream_t stream) {
  const float* z      = (const float*)d_in[0];
  const int* edge_idx = (const int*)d_in[1];
  const int* edge_typ = (const int*)d_in[2];
  const float* w1_l1  = (const float*)d_in[3];
  const float* w1_l2  = (const float*)d_in[4];
  const float* w2_l1  = (const float*)d_in[5];
  const float* w2_l2  = (const float*)d_in[6];
  float* out = (float*)d_out;

  int n_nodes = in_sizes[0] / IN_DIM;
  int n_edges = in_sizes[2];
  int n_l2    = in_sizes[4];          // 1000*16
  int n_types = n_l2 / L1_DIM;        // 1000

  __half* h1 = (__half*)d_ws;
  __half* h2 = h1 + (size_t)n_nodes * L1_DIM;
  __half* wq = h2 + (size_t)n_nodes * L1_DIM;   // [n_types][32]

  {
    int nblocks_proj = (n_nodes + 63) / 64;   // 782
    int grid = nblocks_proj + 8;              // +8 blocks: build wq
    proj_kernel<<<grid, 256, 0, stream>>>(z, w1_l1, w2_l1, w1_l2, w2_l2,
                                          h1, h2, wq,
                                          n_nodes, n_l2, nblocks_proj);
  }
  {
    // 1024 blocks x 256 pairs x 4 edges = 1,048,576 edges per sweep
    edge_kernel<<<1024, 512, 0, stream>>>(edge_idx, edge_typ, h1, h2, wq,
                                          out, n_edges, n_types);
  }
}